// Round 7
// baseline (18.062 us; speedup 1.0000x reference)
//
#include <hip/hip_runtime.h>

// Grid geometry (compile-time constants from the reference)
#define NXC   2048
#define PMLC  40
#define W     2128                     // NXC + 2*PMLC
#define WV    532                      // float4's per row
#define NWORK (W * WV)                 // 1,132,096 vec4 work units
#define GRID  2048                     // 256 CUs x 8 blocks -> fully resident
#define NTHREADS (GRID * 256)          // 524,288 threads, grid-stride x ~2.16

typedef float f32x4 __attribute__((ext_vector_type(4)));

__global__ __launch_bounds__(256) void wave_step(
    const float* __restrict__ p1,
    const float* __restrict__ p2,
    const float* __restrict__ varray,
    const float* __restrict__ sf,
    const int* __restrict__ xs_p,
    const int* __restrict__ ys_p,
    const int* __restrict__ t_p,
    float* __restrict__ pout,
    float* __restrict__ col)
{
    // XCD swizzle (GRID % 8 == 0 -> trivially bijective): each XCD owns a
    // contiguous band of rows within each grid-stride pass, so up/dn halo
    // rows hit that XCD's private L2.
    const int swz = ((blockIdx.x & 7) << 8) | (blockIdx.x >> 3);
    const int tid0 = (swz << 8) + (int)threadIdx.x;

    constexpr float inv_dx2 = 1.0f / (10.0f * 10.0f);
    constexpr float dt2     = 0.0005f * 0.0005f;

    const int xs = xs_p[0] + PMLC;
    const int ys = ys_p[0] + PMLC;

    for (int v = tid0; v < NWORK; v += NTHREADS) {
        const int i  = v / WV;                 // row
        const int j0 = (v - i * WV) << 2;      // first column of this float4
        const size_t base = (size_t)i * W + j0;

        if (i < 8 || i >= W - 8 || j0 < 8 || j0 >= W - 8) {
            // reference zeros everything outside [8, W-8)
            f32x4 z = {0.f, 0.f, 0.f, 0.f};
            __builtin_nontemporal_store(z, reinterpret_cast<f32x4*>(&pout[base]));
            continue;
        }

        // All loads independent -> one memory epoch, max outstanding requests.
        const f32x4 c  = *reinterpret_cast<const f32x4*>(&p2[base]);
        const f32x4 up = *reinterpret_cast<const f32x4*>(&p2[base - W]);
        const f32x4 dn = *reinterpret_cast<const f32x4*>(&p2[base + W]);
        const f32x4 a1 = *reinterpret_cast<const f32x4*>(&p1[base]);
        const float lft = p2[base - 1];
        const float rgt = p2[base + 4];

        const int vi = min(max(i - PMLC, 0), NXC - 1);
        const float* __restrict__ vr = &varray[(size_t)vi * NXC];

        // velocity row, edge-padded; vectorized in the fully-interior case
        float vav[4];
        const int vj0 = j0 - PMLC;
        if (vj0 >= 0 && vj0 <= NXC - 4) {
            const f32x4 vv = *reinterpret_cast<const f32x4*>(&vr[vj0]);
            vav[0] = vv.x; vav[1] = vv.y; vav[2] = vv.z; vav[3] = vv.w;
        } else {
            #pragma unroll
            for (int k = 0; k < 4; ++k)
                vav[k] = vr[min(max(vj0 + k, 0), NXC - 1)];
        }

        const float cc[6]  = {lft, c.x, c.y, c.z, c.w, rgt};
        const float upk[4] = {up.x, up.y, up.z, up.w};
        const float dnk[4] = {dn.x, dn.y, dn.z, dn.w};
        const float a1k[4] = {a1.x, a1.y, a1.z, a1.w};
        float outk[4];

        #pragma unroll
        for (int k = 0; k < 4; ++k) {
            const float alpha = vav[k] * vav[k] * dt2;
            const float ctr   = cc[k + 1];
            const float lap   = (cc[k] + cc[k + 2] + upk[k] + dnk[k] - 4.0f * ctr) * inv_dx2;
            outk[k] = 2.0f * ctr - a1k[k] + alpha * lap;
        }

        // Fused source injection (source cell (x_s+40, y_s+40) is always interior).
        if (i == xs) {
            const int d = ys - j0;
            if ((unsigned)d < 4u) {
                outk[d] += sf[t_p[0]] * dt2;
            }
        }

        // res[:, 50] = p[40 + r, 90]; 90 = j0 88, lane 2
        if (j0 == 88 && (unsigned)(i - PMLC) < (unsigned)NXC) {
            col[i - PMLC] = outk[2];
        }

        f32x4 outv = {outk[0], outk[1], outk[2], outk[3]};
        __builtin_nontemporal_store(outv, reinterpret_cast<f32x4*>(&pout[base]));
    }
}

extern "C" void kernel_launch(void* const* d_in, const int* in_sizes, int n_in,
                              void* d_out, int out_size, void* d_ws, size_t ws_size,
                              hipStream_t stream) {
    const float* p1 = (const float*)d_in[0];
    const float* p2 = (const float*)d_in[1];
    const float* va = (const float*)d_in[2];
    const float* sf = (const float*)d_in[3];
    const int* xs   = (const int*)d_in[4];
    const int* ys   = (const int*)d_in[5];
    const int* t    = (const int*)d_in[6];

    float* pout = (float*)d_out;                   // W*W elements
    float* col  = (float*)d_out + (size_t)W * W;   // 2048 elements

    wave_step<<<GRID, 256, 0, stream>>>(p1, p2, va, sf, xs, ys, t, pout, col);
}

// Round 8
// 15.872 us; speedup vs baseline: 1.1380x; 1.1380x over previous
//
#include <hip/hip_runtime.h>

// Grid geometry (compile-time constants from the reference)
#define NXC   2048
#define PMLC  40
#define W     2128                    // NXC + 2*PMLC
#define WV    532                     // float4's per row
#define NWORK (W * WV)                // 1,132,096 vec4-threads
#define NBLK  ((NWORK + 255) / 256)   // 4423 blocks

typedef float f32x4 __attribute__((ext_vector_type(4)));

__global__ __launch_bounds__(256) void wave_step(
    const float* __restrict__ p1,
    const float* __restrict__ p2,
    const float* __restrict__ varray,
    const float* __restrict__ sf,
    const int* __restrict__ xs_p,
    const int* __restrict__ ys_p,
    const int* __restrict__ t_p,
    float* __restrict__ pout,
    float* __restrict__ col)
{
    // Bijective XCD-chunk swizzle (T1, m204): each XCD owns a contiguous
    // band of rows so up/dn halo rows hit that XCD's private L2.
    constexpr int q = NBLK / 8, r = NBLK % 8;
    const int xcd = blockIdx.x & 7, pos = blockIdx.x >> 3;
    const int swz = (xcd < r ? xcd * (q + 1) : r * (q + 1) + (xcd - r) * q) + pos;
    const int v = (swz << 8) + (int)threadIdx.x;
    if (v >= NWORK) return;

    const int i  = v / WV;                 // row
    const int j0 = (v - i * WV) << 2;      // first column of this float4
    const size_t base = (size_t)i * W + j0;

    if (i < 8 || i >= W - 8 || j0 < 8 || j0 >= W - 8) {
        // reference zeros everything outside [8, W-8)
        f32x4 z = {0.f, 0.f, 0.f, 0.f};
        __builtin_nontemporal_store(z, reinterpret_cast<f32x4*>(&pout[base]));
        return;
    }

    constexpr float inv_dx2 = 1.0f / (10.0f * 10.0f);
    constexpr float dt2     = 0.0005f * 0.0005f;

    // All loads CACHED (p1/varray benefit from L3 residency across replays;
    // p2 halo reuse through L2). All independent -> one memory epoch.
    const f32x4 c  = *reinterpret_cast<const f32x4*>(&p2[base]);
    const f32x4 up = *reinterpret_cast<const f32x4*>(&p2[base - W]);
    const f32x4 dn = *reinterpret_cast<const f32x4*>(&p2[base + W]);
    const f32x4 a1 = *reinterpret_cast<const f32x4*>(&p1[base]);
    const float lft = p2[base - 1];
    const float rgt = p2[base + 4];

    const int vi = min(max(i - PMLC, 0), NXC - 1);
    const float* __restrict__ vr = &varray[(size_t)vi * NXC];

    // velocity row, edge-padded; vectorized in the common fully-interior case
    float vav[4];
    const int vj0 = j0 - PMLC;
    if (vj0 >= 0 && vj0 <= NXC - 4) {
        const f32x4 vv = *reinterpret_cast<const f32x4*>(&vr[vj0]);
        vav[0] = vv.x; vav[1] = vv.y; vav[2] = vv.z; vav[3] = vv.w;
    } else {
        #pragma unroll
        for (int k = 0; k < 4; ++k)
            vav[k] = vr[min(max(vj0 + k, 0), NXC - 1)];
    }

    const float cc[6]  = {lft, c.x, c.y, c.z, c.w, rgt};
    const float upk[4] = {up.x, up.y, up.z, up.w};
    const float dnk[4] = {dn.x, dn.y, dn.z, dn.w};
    const float a1k[4] = {a1.x, a1.y, a1.z, a1.w};
    float outk[4];

    #pragma unroll
    for (int k = 0; k < 4; ++k) {
        const float alpha = vav[k] * vav[k] * dt2;
        const float ctr   = cc[k + 1];
        const float lap   = (cc[k] + cc[k + 2] + upk[k] + dnk[k] - 4.0f * ctr) * inv_dx2;
        outk[k] = 2.0f * ctr - a1k[k] + alpha * lap;
    }

    // Fused source injection (source cell (x_s+40, y_s+40) is always interior).
    const int xs = xs_p[0] + PMLC;
    const int ys = ys_p[0] + PMLC;
    if (i == xs) {
        const int d = ys - j0;
        if ((unsigned)d < 4u) {
            outk[d] += sf[t_p[0]] * dt2;
        }
    }

    // res[:, 50] = p[PML + r, PML + 50] = p[40 + r, 90]; 90 = j0 88, lane 2
    if (j0 == 88 && (unsigned)(i - PMLC) < (unsigned)NXC) {
        col[i - PMLC] = outk[2];
    }

    // Output is never re-read -> nontemporal store: no L2 write-allocate,
    // keeps p2 halo rows resident, no dirty-line drain at kernel end.
    f32x4 outv = {outk[0], outk[1], outk[2], outk[3]};
    __builtin_nontemporal_store(outv, reinterpret_cast<f32x4*>(&pout[base]));
}

extern "C" void kernel_launch(void* const* d_in, const int* in_sizes, int n_in,
                              void* d_out, int out_size, void* d_ws, size_t ws_size,
                              hipStream_t stream) {
    const float* p1 = (const float*)d_in[0];
    const float* p2 = (const float*)d_in[1];
    const float* va = (const float*)d_in[2];
    const float* sf = (const float*)d_in[3];
    const int* xs   = (const int*)d_in[4];
    const int* ys   = (const int*)d_in[5];
    const int* t    = (const int*)d_in[6];

    float* pout = (float*)d_out;                   // W*W elements
    float* col  = (float*)d_out + (size_t)W * W;   // 2048 elements

    wave_step<<<NBLK, 256, 0, stream>>>(p1, p2, va, sf, xs, ys, t, pout, col);
}